// Round 10
// baseline (332.583 us; speedup 1.0000x reference)
//
#include <hip/hip_runtime.h>

#define T_DIM 4000
#define B_DIM 64
#define C_DIM 64
#define U_DIM 200
#define LOG2E 1.4426950408889634f
#define LN2 0.6931471805599453f

#define PAIRS 2000                 // pair tp = (t=2tp, t=2tp+1)
#define PB_BYTES (PAIRS * 800)     // 1.6 MB per batch (50 lanes x 16 B per pair)
#define NSLOT 20                   // uint4 slots per scan wave: 40 steps in flight
#define EG_BYTES ((size_t)B_DIM * PB_BYTES)      // 102.4 MB
#define BM_WORDS (8 * 4)           // per-bg 250-bit ready bitmap, 4 u64 words x 8 bgs

__device__ __forceinline__ float hw_exp2(float x) { return __builtin_amdgcn_exp2f(x); }
__device__ __forceinline__ float hw_log2(float x) { return __builtin_amdgcn_logf(x); }

template <int CTRL>
__device__ __forceinline__ int dpp_i(int x) {
    return __builtin_amdgcn_update_dpp(0, x, CTRL, 0xF, 0xF, true);
}
template <int CTRL>
__device__ __forceinline__ float dpp_f(float x) {
    return __uint_as_float((unsigned)dpp_i<CTRL>((int)__float_as_uint(x)));
}

__device__ __forceinline__ unsigned rne_bf16(float v) {   // RNE bf16 in hi16 (proven R6-R8)
    unsigned b = __float_as_uint(v);
    return b + 0x7FFFu + ((b >> 16) & 1u);
}
__device__ __forceinline__ unsigned pk_bf16(float lo, float hi) {
    return (rne_bf16(lo) >> 16) | (rne_bf16(hi) & 0xFFFF0000u);
}

// ---- scan cores (R5..R8-proven numerics; ldexp-on-chain replaced by mul with F=2^D) ----
struct ScanState { float A0, A1, A2, A3, F; int S; };

__device__ __forceinline__ void renorm(ScanState& st, int lane) {
    float m = fmaxf(fmaxf(st.A0, st.A1), fmaxf(st.A2, st.A3));
    int e = (int)((__float_as_uint(m) >> 23) & 0xFFu);
    int cand = st.S + e - 127;
    int snb = dpp_i<0x138>(st.S);
    if (lane == 0) snb = -(1 << 28);
    int snew = max(cand, snb);
    int k = st.S - snew;
    st.A0 = ldexpf(st.A0, k);
    st.A1 = ldexpf(st.A1, k);
    st.A2 = ldexpf(st.A2, k);
    st.A3 = ldexpf(st.A3, k);
    st.S = snew;
    st.F = ldexpf(1.0f, min(dpp_i<0x138>(snew) - snew, 60));   // 2^D exact; 0 if D<<0
}

__device__ __forceinline__ void step(ScanState& st, float e0, float e1, float e2, float e3) {
    float sh = fminf(dpp_f<0x138>(st.A3) * st.F, 1.125899906842624e15f);  // 2^50 clamp
    float t0 = st.A0 + sh;
    float t1 = st.A1 + st.A0;
    float t2 = st.A2 + st.A1;
    float t3 = st.A3 + st.A2;
    st.A0 = e0 * t0; st.A1 = e1 * t1; st.A2 = e2 * t2; st.A3 = e3 * t3;
}

__device__ __forceinline__ void brenorm(ScanState& st) {
    float m = fmaxf(fmaxf(st.A0, st.A1), fmaxf(st.A2, st.A3));
    int e = (int)((__float_as_uint(m) >> 23) & 0xFFu);
    int cand = st.S + e - 127;
    int snb = dpp_i<0x130>(st.S);
    int snew = max(cand, snb);
    int k = st.S - snew;
    st.A0 = ldexpf(st.A0, k);
    st.A1 = ldexpf(st.A1, k);
    st.A2 = ldexpf(st.A2, k);
    st.A3 = ldexpf(st.A3, k);
    st.S = snew;
    st.F = ldexpf(1.0f, min(dpp_i<0x130>(snew) - snew, 60));
}

__device__ __forceinline__ void bstep(ScanState& st, float e0, float e1, float e2, float e3) {
    float e4s = fminf(dpp_f<0x130>(e0) * st.F, 1.125899906842624e15f);
    float b0n = dpp_f<0x130>(st.A0);
    float g0 = e0 * st.A0, g1 = e1 * st.A1, g2 = e2 * st.A2, g3 = e3 * st.A3;
    st.A0 = g0 + g1; st.A1 = g1 + g2; st.A2 = g2 + g3; st.A3 = g3 + e4s * b0n;
}

__device__ __forceinline__ ScanState scan_init(const float* in, const int* tgt, int lane, int b) {
    float v0 = in[b * 64 + (tgt[b * U_DIM] & 63)];
    ScanState st;
    st.A0 = (lane == 0) ? hw_exp2(v0 * LOG2E) : 0.0f;
    st.A1 = 0.0f; st.A2 = 0.0f; st.A3 = 0.0f;
    st.S = 0; st.F = 1.0f;
    return st;
}

#define LO(x) __uint_as_float((x) << 16)
#define HI(x) __uint_as_float((x) & 0xFFFF0000u)

// Fused producer-consumer kernel.
//   blocks 0..63      : scan for batch b = blockIdx (wave0 fwd t=1..2000, wave1 bwd t=3999..2001,
//                       waves 2,3 barrier+exit); consumption gated on ready-bitmap.
//   blocks 64..2063   : prep chunk (bg = id&7, tc interleaved 0,249,1,248,...):
//                       stage 16 t-rows x 8 b -> LDS exp2 tile -> Eg emit + row-lse,
//                       then release-atomicOr the ready bit.
__global__ __launch_bounds__(256, 1) void fused_kernel(const float* __restrict__ in,
                                                       const int* __restrict__ tgt,
                                                       unsigned* __restrict__ eg,
                                                       unsigned long long* __restrict__ bm,
                                                       float* __restrict__ out) {
    __shared__ float ex[16 * 8 * 68];
    __shared__ unsigned tgc[400];
    __shared__ float red[4];
    // scan junction buffers (disjoint use: scan blocks never touch ex/tgc)
    __shared__ float jb0[64], jb1[64], jb2[64], jb3[64];
    __shared__ int jsb[64];

    if (blockIdx.x < 64) {
        // ================= scan =================
        const int wv = threadIdx.x >> 6;
        if (wv >= 2) { __syncthreads(); return; }
        const int lane = threadIdx.x & 63;
        const int b = blockIdx.x;
        const int lidx = (lane < 50) ? lane : 49;
        const char* egb = (const char*)eg + (size_t)b * PB_BYTES;
        const unsigned long long* bmg = bm + (b >> 3) * 4;

        ScanState st;
        if (wv == 1) {
            // -------- backward: pairs 1999 .. 1000(hi only) --------
            st.A0 = 0.0f; st.A1 = 0.0f; st.A2 = 0.0f;
            st.A3 = (lane == 49) ? 1.0f : 0.0f;
            st.S = 0; st.F = 1.0f;
            int lowB = 250;                        // chunks [lowB,250) verified ready
            int off = 1999 * 800 + lidx * 16;
            uint4 wb[NSLOT];
            // need chunks 247..249 for pairs 1999..1980
            while (lowB > 247) {
                int ch = lowB - 1;
                unsigned long long v = __hip_atomic_load(&bmg[ch >> 6], __ATOMIC_ACQUIRE,
                                                         __HIP_MEMORY_SCOPE_AGENT);
                unsigned long long inv = ~(v << (63 - (ch & 63)));
                int add = inv ? __builtin_clzll(inv) : ((ch & 63) + 1);
                if (!add) __builtin_amdgcn_s_sleep(1);
                lowB -= add;
            }
            #pragma unroll
            for (int j = 0; j < NSLOT; ++j) { wb[j] = *(const uint4*)(egb + off); off -= 800; }
            for (int k = 0; k < 49; ++k) {
                int need = (1960 - 20 * k) >> 3;   // lowest chunk this iter's refills touch
                while (lowB > need) {
                    int ch = lowB - 1;
                    unsigned long long v = __hip_atomic_load(&bmg[ch >> 6], __ATOMIC_ACQUIRE,
                                                             __HIP_MEMORY_SCOPE_AGENT);
                    unsigned long long inv = ~(v << (63 - (ch & 63)));
                    int add = inv ? __builtin_clzll(inv) : ((ch & 63) + 1);
                    if (!add) __builtin_amdgcn_s_sleep(1);
                    lowB -= add;
                }
                #pragma unroll
                for (int j = 0; j < NSLOT; ++j) {
                    if ((j & 3) == 0) brenorm(st);
                    uint4 w = wb[j];
                    wb[j] = *(const uint4*)(egb + off); off -= 800;
                    bstep(st, LO(w.z), HI(w.z), LO(w.w), HI(w.w));
                    bstep(st, LO(w.x), HI(w.x), LO(w.y), HI(w.y));
                }
            }
            #pragma unroll
            for (int j = 0; j < NSLOT; ++j) {      // pairs 1019..1001 full, 1000 hi-only
                if ((j & 3) == 0) brenorm(st);
                uint4 w = wb[j];
                bstep(st, LO(w.z), HI(w.z), LO(w.w), HI(w.w));
                if (j < NSLOT - 1) bstep(st, LO(w.x), HI(w.x), LO(w.y), HI(w.y));
            }
            brenorm(st);
            jb0[lane] = st.A0; jb1[lane] = st.A1; jb2[lane] = st.A2; jb3[lane] = st.A3;
            jsb[lane] = st.S;
            __syncthreads();
        } else {
            // -------- forward: t=1 (pair0 hi), pairs 1..999, pair 1000 lo --------
            st = scan_init(in, tgt, lane, b);
            int readyF = 0;                        // chunks [0,readyF) verified ready
            int off = 800 + lidx * 16;
            uint4 wb[NSLOT];
            while (readyF <= 2) {                  // pairs 0..20 -> chunks 0..2
                unsigned long long v = __hip_atomic_load(&bmg[readyF >> 6], __ATOMIC_ACQUIRE,
                                                         __HIP_MEMORY_SCOPE_AGENT);
                unsigned long long inv = ~(v >> (readyF & 63));
                int add = inv ? __builtin_ctzll(inv) : (64 - (readyF & 63));
                if (!add) __builtin_amdgcn_s_sleep(1);
                readyF += add;
            }
            #pragma unroll
            for (int j = 0; j < NSLOT; ++j) { wb[j] = *(const uint4*)(egb + off); off += 800; }
            uint2 h0 = *(const uint2*)(egb + lidx * 16 + 8);
            step(st, LO(h0.x), HI(h0.x), LO(h0.y), HI(h0.y));    // t = 1
            for (int k = 0; k < 49; ++k) {
                int need = (40 + 20 * k) >> 3;     // highest chunk this iter's refills touch
                while (readyF <= need) {
                    unsigned long long v = __hip_atomic_load(&bmg[readyF >> 6], __ATOMIC_ACQUIRE,
                                                             __HIP_MEMORY_SCOPE_AGENT);
                    unsigned long long inv = ~(v >> (readyF & 63));
                    int add = inv ? __builtin_ctzll(inv) : (64 - (readyF & 63));
                    if (!add) __builtin_amdgcn_s_sleep(1);
                    readyF += add;
                }
                #pragma unroll
                for (int j = 0; j < NSLOT; ++j) {
                    if ((j & 3) == 0) renorm(st, lane);
                    uint4 w = wb[j];
                    wb[j] = *(const uint4*)(egb + off); off += 800;
                    step(st, LO(w.x), HI(w.x), LO(w.y), HI(w.y));
                    step(st, LO(w.z), HI(w.z), LO(w.w), HI(w.w));
                }
            }
            #pragma unroll
            for (int j = 0; j < NSLOT; ++j) {      // pairs 981..999 full, 1000 lo-only
                if ((j & 3) == 0) renorm(st, lane);
                uint4 w = wb[j];
                step(st, LO(w.x), HI(w.x), LO(w.y), HI(w.y));
                if (j < NSLOT - 1) step(st, LO(w.z), HI(w.z), LO(w.w), HI(w.w));
            }
            renorm(st, lane);
            __syncthreads();
            // junction: -log2( sum_u alpha_2000[u] * beta_2001[u] )
            float d = st.A0 * jb0[lane] + st.A1 * jb1[lane]
                    + st.A2 * jb2[lane] + st.A3 * jb3[lane];
            float ll = (lane < 50) ? hw_log2(fmaxf(d, 1e-38f)) + (float)(st.S + jsb[lane])
                                   : -1e30f;
            float mx = ll;
            #pragma unroll
            for (int o = 32; o > 0; o >>= 1) mx = fmaxf(mx, __shfl_xor(mx, o));
            float s = (lane < 50) ? hw_exp2(ll - mx) : 0.0f;
            #pragma unroll
            for (int o = 32; o > 0; o >>= 1) s += __shfl_xor(s, o);
            if (lane == 0) atomicAdd(out, -(mx + hw_log2(s)) * (LN2 / 64.0f));
        }
        return;
    }

    // ================= prep =================
    const int tid = threadIdx.x;
    const int id = blockIdx.x - 64;
    const int bg = id & 7;
    const int jj = id >> 3;                        // 0..249
    const int tc = (jj & 1) ? (249 - (jj >> 1)) : (jj >> 1);   // 0,249,1,248,...
    const int t0 = tc * 16, b0 = bg * 8;

    for (int o = tid; o < 400; o += 256) {
        int4 tv = ((const int4*)tgt)[bg * 400 + o];
        tgc[o] = (unsigned)(tv.x & 63) | ((unsigned)(tv.y & 63) << 8)
               | ((unsigned)(tv.z & 63) << 16) | ((unsigned)(tv.w & 63) << 24);
    }
    #pragma unroll
    for (int k = 0; k < 8; ++k) {
        int flat = k * 256 + tid;
        int t_l = flat >> 7, i = flat & 127, b_l = i >> 4, q = i & 15;
        float4 v = *(const float4*)(in + (size_t)(t0 + t_l) * 4096 + (b0 + b_l) * 64 + q * 4);
        float4 e;
        e.x = hw_exp2(v.x * LOG2E); e.y = hw_exp2(v.y * LOG2E);
        e.z = hw_exp2(v.z * LOG2E); e.w = hw_exp2(v.w * LOG2E);
        *(float4*)&ex[(t_l * 8 + b_l) * 68 + q * 4] = e;
    }
    __syncthreads();

    {   // row-lse: threads 0..127 own one (t,b) row each
        float v = 0.0f;
        if (tid < 128) {
            const float4* p = (const float4*)&ex[tid * 68];
            float s = 0.0f;
            #pragma unroll
            for (int j = 0; j < 16; ++j) { float4 a = p[j]; s += (a.x + a.y) + (a.z + a.w); }
            v = hw_log2(s);
        }
        #pragma unroll
        for (int o = 32; o > 0; o >>= 1) v += __shfl_xor(v, o);
        if ((tid & 63) == 0) red[tid >> 6] = v;
    }

    for (int it = 0; it < 13; ++it) {
        int o = it * 256 + tid;
        if (o < 3200) {
            int l = o % 50;
            int rest = o / 50;
            int b_l = rest & 7, tp_l = rest >> 3;
            unsigned tw = tgc[b_l * 50 + l];
            int c0 = tw & 255, c1 = (tw >> 8) & 255, c2 = (tw >> 16) & 255, c3 = tw >> 24;
            const float* plo = &ex[(tp_l * 16 + b_l) * 68];
            const float* phi = plo + 8 * 68;
            uint4 w;
            w.x = pk_bf16(plo[c0], plo[c1]);
            w.y = pk_bf16(plo[c2], plo[c3]);
            w.z = pk_bf16(phi[c0], phi[c1]);
            w.w = pk_bf16(phi[c2], phi[c3]);
            *(uint4*)((char*)eg + (size_t)(b0 + b_l) * PB_BYTES
                      + (size_t)(tc * 8 + tp_l) * 800 + l * 16) = w;
        }
    }
    __syncthreads();
    if (tid == 0) {
        atomicAdd(out, (red[0] + red[1] + red[2] + red[3]) * (LN2 / 64.0f));
        __threadfence();                            // all block stores visible device-wide
        __hip_atomic_fetch_or(&bm[bg * 4 + (tc >> 6)], 1ULL << (tc & 63),
                              __ATOMIC_RELEASE, __HIP_MEMORY_SCOPE_AGENT);
    }
}

// ---- fallback pair (no-workspace path; proven forward core) ----
__global__ __launch_bounds__(256) void lse_sum_kernel(const float* __restrict__ in,
                                                      float* __restrict__ out) {
    const int lane = threadIdx.x & 63;
    const int w = threadIdx.x >> 6;
    const int wid = blockIdx.x * 4 + w;
    const int ROWS = (T_DIM * B_DIM) / 1024;
    const float* p = in + (size_t)wid * ROWS * 64 + lane;
    float acc = 0.0f;
    for (int i = 0; i < ROWS; i += 2) {
        float xa = p[(size_t)i * 64];
        float xb = p[(size_t)(i + 1) * 64];
        float ea = hw_exp2(xa * LOG2E);
        float eb = hw_exp2(xb * LOG2E);
        #pragma unroll
        for (int off = 32; off > 0; off >>= 1) {
            ea += __shfl_xor(ea, off);
            eb += __shfl_xor(eb, off);
        }
        acc += hw_log2(ea) + hw_log2(eb);
    }
    __shared__ float red[4];
    if (lane == 0) red[w] = acc;
    __syncthreads();
    if (threadIdx.x == 0)
        atomicAdd(out, (red[0] + red[1] + red[2] + red[3]) * (LN2 / 64.0f));
}

__global__ __launch_bounds__(64) void scan_fb(const float* __restrict__ in,
                                              const int* __restrict__ tgt,
                                              float* __restrict__ out) {
    const int lane = threadIdx.x;
    const int b = blockIdx.x;
    const int lidx = (lane < 50) ? lane : 49;
    int4 tg = ((const int4*)(tgt + b * U_DIM))[lidx];
    tg.x &= 63; tg.y &= 63; tg.z &= 63; tg.w &= 63;
    ScanState st = scan_init(in, tgt, lane, b);
    const char* inb = (const char*)in;
    int o0 = 16384 + b * 256 + tg.x * 4;
    int o1 = 16384 + b * 256 + tg.y * 4;
    int o2 = 16384 + b * 256 + tg.z * 4;
    int o3 = 16384 + b * 256 + tg.w * 4;
    const int m0 = 3999 * 16384 + b * 256 + tg.x * 4;
    const int m1 = m0 + (tg.y - tg.x) * 4;
    const int m2 = m0 + (tg.z - tg.x) * 4;
    const int m3 = m0 + (tg.w - tg.x) * 4;
    float f0[16], f1[16], f2[16], f3[16];
    #pragma unroll
    for (int j = 0; j < 16; ++j) {
        f0[j] = *(const float*)(inb + min(o0, m0)); o0 += 16384;
        f1[j] = *(const float*)(inb + min(o1, m1)); o1 += 16384;
        f2[j] = *(const float*)(inb + min(o2, m2)); o2 += 16384;
        f3[j] = *(const float*)(inb + min(o3, m3)); o3 += 16384;
    }
    for (int k = 0; k < 249; ++k) {
        #pragma unroll
        for (int j = 0; j < 16; ++j) {
            if (j == 0 || j == 8) renorm(st, lane);
            float e0 = hw_exp2(f0[j] * LOG2E);
            float e1 = hw_exp2(f1[j] * LOG2E);
            float e2 = hw_exp2(f2[j] * LOG2E);
            float e3 = hw_exp2(f3[j] * LOG2E);
            f0[j] = *(const float*)(inb + min(o0, m0)); o0 += 16384;
            f1[j] = *(const float*)(inb + min(o1, m1)); o1 += 16384;
            f2[j] = *(const float*)(inb + min(o2, m2)); o2 += 16384;
            f3[j] = *(const float*)(inb + min(o3, m3)); o3 += 16384;
            step(st, e0, e1, e2, e3);
        }
    }
    #pragma unroll
    for (int j = 0; j < 15; ++j) {
        if (j == 0 || j == 8) renorm(st, lane);
        float e0 = hw_exp2(f0[j] * LOG2E);
        float e1 = hw_exp2(f1[j] * LOG2E);
        float e2 = hw_exp2(f2[j] * LOG2E);
        float e3 = hw_exp2(f3[j] * LOG2E);
        step(st, e0, e1, e2, e3);
    }
    if (lane == 49) {
        float a2 = hw_log2(fmaxf(st.A3, 1e-38f)) + (float)st.S;
        atomicAdd(out, -a2 * (LN2 / 64.0f));
    }
}

extern "C" void kernel_launch(void* const* d_in, const int* in_sizes, int n_in,
                              void* d_out, int out_size, void* d_ws, size_t ws_size,
                              hipStream_t stream) {
    const float* inputs = (const float*)d_in[0];   // (T, B, C) fp32
    const int* targets = (const int*)d_in[1];      // (B, U) int32
    float* out = (float*)d_out;                    // scalar fp32

    (void)hipMemsetAsync(out, 0, sizeof(float), stream);

    if (ws_size >= EG_BYTES + BM_WORDS * sizeof(unsigned long long)) {
        unsigned* eg = (unsigned*)d_ws;
        unsigned long long* bmp = (unsigned long long*)((char*)d_ws + EG_BYTES);
        (void)hipMemsetAsync(bmp, 0, BM_WORDS * sizeof(unsigned long long), stream);
        fused_kernel<<<64 + 2000, 256, 0, stream>>>(inputs, targets, eg, bmp, out);
    } else {
        scan_fb<<<B_DIM, 64, 0, stream>>>(inputs, targets, out);
        lse_sum_kernel<<<256, 256, 0, stream>>>(inputs, out);
    }
}